// Round 2
// baseline (354.999 us; speedup 1.0000x reference)
//
#include <hip/hip_runtime.h>
#include <hip/hip_bf16.h>

#define D_MODEL 1024
#define NH 16
#define HD 64
#define S_LEN 2048
#define NB 2
#define M_TOT (NB * S_LEN)   // 4096
#define N3 (3 * D_MODEL)     // 3072

typedef __attribute__((ext_vector_type(8))) short bf16x8;
typedef __attribute__((ext_vector_type(4))) float f32x4;
typedef __attribute__((ext_vector_type(4))) unsigned short u16x4;

__device__ __forceinline__ unsigned short f2bf(float f) {
    unsigned int u = __float_as_uint(f);
    u += 0x7fffu + ((u >> 16) & 1u);   // round-to-nearest-even
    return (unsigned short)(u >> 16);
}

// ---------------------------------------------------------------- cast f32 -> bf16
__global__ __launch_bounds__(256) void cast_f32_bf16(
    const float* __restrict__ in, unsigned short* __restrict__ out, int n4) {
    int i = blockIdx.x * 256 + threadIdx.x;
    if (i < n4) {
        float4 v = reinterpret_cast<const float4*>(in)[i];
        u16x4 o;
        o.x = f2bf(v.x); o.y = f2bf(v.y); o.z = f2bf(v.z); o.w = f2bf(v.w);
        reinterpret_cast<u16x4*>(out)[i] = o;
    }
}

// ---------------------------------------------------------------- QKV GEMM
// z = x * W^T + b.  A = xb [4096][1024] bf16 (K-major), B = Wb [3072][1024] bf16 (K-major).
// 128x128 tile, BK=64, 4 waves (2x2), each wave 64x64 = 4x4 frags of 16x16x32 MFMA.
#define BM 128
#define BN 128
#define BK 64

__global__ __launch_bounds__(256) void qkv_gemm(
    const unsigned short* __restrict__ A, const unsigned short* __restrict__ B,
    const float* __restrict__ bias, unsigned short* __restrict__ Z) {
    __shared__ unsigned short As[BM * BK];   // 16 KB, XOR-swizzled 16B slots
    __shared__ unsigned short Bs[BN * BK];   // 16 KB

    const int t = threadIdx.x;
    const int lane = t & 63;
    const int wid = t >> 6;
    const int wr = wid >> 1, wc = wid & 1;
    const int bm = blockIdx.y, bn = blockIdx.x;
    const int lr = lane & 15;   // frag row/col
    const int lg = lane >> 4;   // k-group

    f32x4 acc[4][4] = {};

    for (int k0 = 0; k0 < 1024; k0 += BK) {
        __syncthreads();   // protect previous iteration's reads
#pragma unroll
        for (int p = 0; p < 4; ++p) {
            int idx = p * 256 + t;        // 0..1023
            int row = idx >> 3;           // 0..127
            int cg  = idx & 7;            // 16B slot in row
            int scg = cg ^ (row & 7);     // swizzled slot
            bf16x8 va = *reinterpret_cast<const bf16x8*>(
                &A[(size_t)(bm * BM + row) * 1024 + k0 + cg * 8]);
            *reinterpret_cast<bf16x8*>(&As[row * BK + scg * 8]) = va;
            bf16x8 vb = *reinterpret_cast<const bf16x8*>(
                &B[(size_t)(bn * BN + row) * 1024 + k0 + cg * 8]);
            *reinterpret_cast<bf16x8*>(&Bs[row * BK + scg * 8]) = vb;
        }
        __syncthreads();
#pragma unroll
        for (int ks = 0; ks < 2; ++ks) {
            bf16x8 af[4], bfr[4];
#pragma unroll
            for (int m = 0; m < 4; ++m) {
                int row = wr * 64 + m * 16 + lr;
                int slot = (ks * 4 + lg) ^ (row & 7);
                af[m] = *reinterpret_cast<const bf16x8*>(&As[row * BK + slot * 8]);
            }
#pragma unroll
            for (int n = 0; n < 4; ++n) {
                int row = wc * 64 + n * 16 + lr;
                int slot = (ks * 4 + lg) ^ (row & 7);
                bfr[n] = *reinterpret_cast<const bf16x8*>(&Bs[row * BK + slot * 8]);
            }
#pragma unroll
            for (int m = 0; m < 4; ++m)
#pragma unroll
                for (int n = 0; n < 4; ++n)
                    acc[m][n] = __builtin_amdgcn_mfma_f32_16x16x32_bf16(
                        af[m], bfr[n], acc[m][n], 0, 0, 0);
        }
    }
    // epilogue: + bias, -> bf16.  D map: row=(lane>>4)*4+i, col=lane&15
#pragma unroll
    for (int m = 0; m < 4; ++m) {
        int row = bm * BM + wr * 64 + m * 16 + lg * 4;
#pragma unroll
        for (int n = 0; n < 4; ++n) {
            int col = bn * BN + wc * 64 + n * 16 + lr;
            float bv = bias[col];
#pragma unroll
            for (int i = 0; i < 4; ++i) {
                Z[(size_t)(row + i) * N3 + col] = f2bf(acc[m][n][i] + bv);
            }
        }
    }
}

// ---------------------------------------------------------------- V transpose
// Vt[nh][d][c] = Z[n*2048 + c][2048 + h*64 + d]
__global__ __launch_bounds__(256) void transpose_v(
    const unsigned short* __restrict__ Z, unsigned short* __restrict__ Vt) {
    __shared__ unsigned short tile[64][72];
    int bid = blockIdx.x;
    int nh = bid >> 5;           // 0..31
    int cb = bid & 31;           // 0..31 (c block of 64)
    int n = nh >> 4, h = nh & 15;
    int t = threadIdx.x;
#pragma unroll
    for (int p = 0; p < 4; ++p) {
        int idx = p * 256 + t;    // 0..1023
        int r = idx >> 4;         // c row 0..63
        int cg = idx & 15;        // 4-col group along d
        u16x4 v = *reinterpret_cast<const u16x4*>(
            &Z[(size_t)(n * S_LEN + cb * 64 + r) * N3 + 2 * D_MODEL + h * HD + cg * 4]);
        *reinterpret_cast<u16x4*>(&tile[r][cg * 4]) = v;
    }
    __syncthreads();
#pragma unroll
    for (int p = 0; p < 4; ++p) {
        int idx = p * 256 + t;
        int d = idx >> 4;         // 0..63
        int cg = idx & 15;        // 4-col group along c
        u16x4 o;
        o.x = tile[cg * 4 + 0][d];
        o.y = tile[cg * 4 + 1][d];
        o.z = tile[cg * 4 + 2][d];
        o.w = tile[cg * 4 + 3][d];
        *reinterpret_cast<u16x4*>(
            &Vt[((size_t)nh * 64 + d) * S_LEN + cb * 64 + cg * 4]) = o;
    }
}

// ---------------------------------------------------------------- flash attention
// grid (qb=32, nh=32); block 256 = 4 waves; wave w owns q rows [qb*64+w*16, +16)
__global__ __launch_bounds__(256) void attn(
    const unsigned short* __restrict__ Z, const unsigned short* __restrict__ Vt,
    float* __restrict__ Out) {
    const int qb = blockIdx.x;
    const int nh = blockIdx.y;
    const int n = nh >> 4, h = nh & 15;
    const int t = threadIdx.x;
    const int lane = t & 63, w = t >> 6;
    const int lr = lane & 15, lg = lane >> 4;

    __shared__ unsigned short p_lds[4][16][72];   // per-wave P tile (padded)

    // hoist Q fragments (A-operand: row = lane&15, k = (lane>>4)*8 + j)
    const size_t zrowQ = (size_t)(n * S_LEN + qb * 64 + w * 16 + lr) * N3 + D_MODEL + h * HD;
    bf16x8 qf[2];
    qf[0] = *reinterpret_cast<const bf16x8*>(&Z[zrowQ + lg * 8]);
    qf[1] = *reinterpret_cast<const bf16x8*>(&Z[zrowQ + 32 + lg * 8]);

    f32x4 o[4] = {};
    float mrun[4], lrun[4];
#pragma unroll
    for (int i = 0; i < 4; ++i) { mrun[i] = -1e30f; lrun[i] = 0.f; }

    const int qrow_base = qb * 64 + w * 16 + lg * 4;   // + i

    for (int kb = 0; kb <= qb; ++kb) {
        // ---- S = Q K^T  (D: row=q, col=key)
        f32x4 s[4];
#pragma unroll
        for (int cf = 0; cf < 4; ++cf) {
            const size_t zrowK = (size_t)(n * S_LEN + kb * 64 + cf * 16 + lr) * N3 + h * HD;
            bf16x8 kf0 = *reinterpret_cast<const bf16x8*>(&Z[zrowK + lg * 8]);
            bf16x8 kf1 = *reinterpret_cast<const bf16x8*>(&Z[zrowK + 32 + lg * 8]);
            f32x4 a = {};
            a = __builtin_amdgcn_mfma_f32_16x16x32_bf16(qf[0], kf0, a, 0, 0, 0);
            a = __builtin_amdgcn_mfma_f32_16x16x32_bf16(qf[1], kf1, a, 0, 0, 0);
            s[cf] = a;
        }
        // ---- scale + causal mask (only diagonal block needs the mask)
        const bool diag = (kb == qb);
#pragma unroll
        for (int cf = 0; cf < 4; ++cf) {
            int kcol = kb * 64 + cf * 16 + lr;
#pragma unroll
            for (int i = 0; i < 4; ++i) {
                float v = s[cf][i] * 0.03125f;   // 1/sqrt(1024)
                if (diag && kcol > qrow_base + i) v = -1e30f;
                s[cf][i] = v;
            }
        }
        // ---- online softmax per q-row (rows live in 16-lane groups)
#pragma unroll
        for (int i = 0; i < 4; ++i) {
            float v = fmaxf(fmaxf(s[0][i], s[1][i]), fmaxf(s[2][i], s[3][i]));
            v = fmaxf(v, __shfl_xor(v, 1));
            v = fmaxf(v, __shfl_xor(v, 2));
            v = fmaxf(v, __shfl_xor(v, 4));
            v = fmaxf(v, __shfl_xor(v, 8));
            float mn = fmaxf(mrun[i], v);
            float corr = __expf(mrun[i] - mn);
            mrun[i] = mn;
            float sum = 0.f;
#pragma unroll
            for (int cf = 0; cf < 4; ++cf) {
                float p = __expf(s[cf][i] - mn);
                s[cf][i] = p;
                sum += p;
            }
            sum += __shfl_xor(sum, 1);
            sum += __shfl_xor(sum, 2);
            sum += __shfl_xor(sum, 4);
            sum += __shfl_xor(sum, 8);
            lrun[i] = lrun[i] * corr + sum;
#pragma unroll
            for (int cfd = 0; cfd < 4; ++cfd) o[cfd][i] *= corr;
        }
        // ---- P (D-layout) -> LDS -> A-layout.  Per-wave private: DS ops are
        // in-order within a wave, no barrier needed.
#pragma unroll
        for (int cf = 0; cf < 4; ++cf)
#pragma unroll
            for (int i = 0; i < 4; ++i)
                p_lds[w][lg * 4 + i][cf * 16 + lr] = f2bf(s[cf][i]);
        // ---- O += P * V   (B-operand from Vt: col=d, k=key)
#pragma unroll
        for (int ks = 0; ks < 2; ++ks) {
            bf16x8 pf = *reinterpret_cast<const bf16x8*>(&p_lds[w][lr][ks * 32 + lg * 8]);
#pragma unroll
            for (int cfd = 0; cfd < 4; ++cfd) {
                const size_t vrow =
                    ((size_t)nh * 64 + cfd * 16 + lr) * S_LEN + kb * 64 + ks * 32 + lg * 8;
                bf16x8 vf = *reinterpret_cast<const bf16x8*>(&Vt[vrow]);
                o[cfd] = __builtin_amdgcn_mfma_f32_16x16x32_bf16(pf, vf, o[cfd], 0, 0, 0);
            }
        }
    }
    // ---- epilogue: out = O / l
#pragma unroll
    for (int cfd = 0; cfd < 4; ++cfd) {
        int d = h * HD + cfd * 16 + lr;
#pragma unroll
        for (int i = 0; i < 4; ++i) {
            int q = qb * 64 + w * 16 + lg * 4 + i;
            Out[(size_t)(n * S_LEN + q) * D_MODEL + d] = o[cfd][i] / lrun[i];
        }
    }
}

// ----------------------------------------------------------------
extern "C" void kernel_launch(void* const* d_in, const int* in_sizes, int n_in,
                              void* d_out, int out_size, void* d_ws, size_t ws_size,
                              hipStream_t stream) {
    const float* x = (const float*)d_in[0];   // [2,2048,1024]
    const float* W = (const float*)d_in[1];   // [3072,1024]
    const float* b = (const float*)d_in[2];   // [3072]
    float* out = (float*)d_out;               // [2,2048,1024] f32

    char* ws = (char*)d_ws;
    unsigned short* xb = (unsigned short*)ws;                                  // 8 MB
    unsigned short* Wb = (unsigned short*)(ws + (size_t)8 * 1024 * 1024);      // 6 MB
    unsigned short* Z  = (unsigned short*)(ws + (size_t)14 * 1024 * 1024);     // 24 MB
    unsigned short* Vt = (unsigned short*)(ws + (size_t)38 * 1024 * 1024);     // 8 MB

    cast_f32_bf16<<<4096, 256, 0, stream>>>(x, xb, M_TOT * D_MODEL / 4);
    cast_f32_bf16<<<3072, 256, 0, stream>>>(W, Wb, N3 * D_MODEL / 4);
    qkv_gemm<<<dim3(N3 / BN, M_TOT / BM), 256, 0, stream>>>(xb, Wb, b, Z);
    transpose_v<<<1024, 256, 0, stream>>>(Z, Vt);
    attn<<<dim3(S_LEN / 64, NB * NH), 256, 0, stream>>>(Z, Vt, out);
}

// Round 3
// 189.119 us; speedup vs baseline: 1.8771x; 1.8771x over previous
//
#include <hip/hip_runtime.h>
#include <hip/hip_bf16.h>

#define D_MODEL 1024
#define NH 16
#define HD 64
#define S_LEN 2048
#define NB 2
#define M_TOT 4096
#define N3 3072

typedef __attribute__((ext_vector_type(8))) short bf16x8;
typedef __attribute__((ext_vector_type(4))) float f32x4;
typedef __attribute__((ext_vector_type(4))) unsigned short u16x4;

__device__ __forceinline__ unsigned short f2bf(float f) {
    unsigned int u = __float_as_uint(f);
    u += 0x7fffu + ((u >> 16) & 1u);
    return (unsigned short)(u >> 16);
}

// async global->LDS, 16B per lane; LDS dest = wave-uniform base + lane*16,
// global src is per-lane (pre-swizzled source pattern, m173).
#define GLOAD_LDS(gp, lp)                                                      \
    __builtin_amdgcn_global_load_lds(                                          \
        (const __attribute__((address_space(1))) void*)(gp),                   \
        (__attribute__((address_space(3))) void*)(lp), 16, 0, 0)

// ---------------------------------------------------------------- cast f32 -> bf16
__global__ __launch_bounds__(256) void cast_f32_bf16(
    const float* __restrict__ in, unsigned short* __restrict__ out, int n4) {
    int i = blockIdx.x * 256 + threadIdx.x;
    if (i < n4) {
        float4 v = reinterpret_cast<const float4*>(in)[i];
        u16x4 o;
        o.x = f2bf(v.x); o.y = f2bf(v.y); o.z = f2bf(v.z); o.w = f2bf(v.w);
        reinterpret_cast<u16x4*>(out)[i] = o;
    }
}

// ---------------------------------------------------------------- QKV GEMM
// m97 structure: linear LDS dest via global_load_lds(16B), XOR swizzle applied
// on the SOURCE address; reads use slot = seg ^ (row&7).
#define BM 128
#define BN 128
#define BK 64

__global__ __launch_bounds__(256) void qkv_gemm(
    const unsigned short* __restrict__ A, const unsigned short* __restrict__ B,
    const float* __restrict__ bias, unsigned short* __restrict__ Z) {
    __shared__ unsigned short As[BM * BK];   // [128][64] bf16, 16 KB
    __shared__ unsigned short Bs[BN * BK];

    const int t = threadIdx.x;
    const int lane = t & 63;
    const int wid = t >> 6;
    const int wr = wid >> 1, wc = wid & 1;
    const int bm = blockIdx.y, bn = blockIdx.x;
    const int lr = lane & 15;
    const int lg = lane >> 4;
    const int srow = lane >> 3;   // 0..7 within an 8-row staging issue
    const int sslot = lane & 7;   // linear LDS 16B slot

    f32x4 acc[4][4] = {};

    for (int k0 = 0; k0 < 1024; k0 += BK) {
        __syncthreads();
#pragma unroll
        for (int p = 0; p < 4; ++p) {
            int rb = wid * 32 + p * 8;          // wave-uniform row base
            int row = rb + srow;
            int seg = sslot ^ (row & 7);        // inverse swizzle on source
            GLOAD_LDS(&A[(size_t)(bm * BM + row) * 1024 + k0 + seg * 8],
                      &As[rb * BK]);
            GLOAD_LDS(&B[(size_t)(bn * BN + row) * 1024 + k0 + seg * 8],
                      &Bs[rb * BK]);
        }
        __syncthreads();
#pragma unroll
        for (int ks = 0; ks < 2; ++ks) {
            bf16x8 af[4], bfr[4];
#pragma unroll
            for (int m = 0; m < 4; ++m) {
                int row = wr * 64 + m * 16 + lr;
                int slot = (ks * 4 + lg) ^ (row & 7);
                af[m] = *reinterpret_cast<const bf16x8*>(&As[row * BK + slot * 8]);
            }
#pragma unroll
            for (int n = 0; n < 4; ++n) {
                int row = wc * 64 + n * 16 + lr;
                int slot = (ks * 4 + lg) ^ (row & 7);
                bfr[n] = *reinterpret_cast<const bf16x8*>(&Bs[row * BK + slot * 8]);
            }
#pragma unroll
            for (int m = 0; m < 4; ++m)
#pragma unroll
                for (int n = 0; n < 4; ++n)
                    acc[m][n] = __builtin_amdgcn_mfma_f32_16x16x32_bf16(
                        af[m], bfr[n], acc[m][n], 0, 0, 0);
        }
    }
#pragma unroll
    for (int m = 0; m < 4; ++m) {
        int row = bm * BM + wr * 64 + m * 16 + lg * 4;
#pragma unroll
        for (int n = 0; n < 4; ++n) {
            int col = bn * BN + wc * 64 + n * 16 + lr;
            float bv = bias[col];
#pragma unroll
            for (int i = 0; i < 4; ++i) {
                Z[(size_t)(row + i) * N3 + col] = f2bf(acc[m][n][i] + bv);
            }
        }
    }
}

// ---------------------------------------------------------------- V transpose
__global__ __launch_bounds__(256) void transpose_v(
    const unsigned short* __restrict__ Z, unsigned short* __restrict__ Vt) {
    __shared__ unsigned short tile[64][72];
    int bid = blockIdx.x;
    int nh = bid >> 5;
    int cb = bid & 31;
    int n = nh >> 4, h = nh & 15;
    int t = threadIdx.x;
#pragma unroll
    for (int p = 0; p < 4; ++p) {
        int idx = p * 256 + t;
        int r = idx >> 4;
        int cg = idx & 15;
        u16x4 v = *reinterpret_cast<const u16x4*>(
            &Z[(size_t)(n * S_LEN + cb * 64 + r) * N3 + 2 * D_MODEL + h * HD + cg * 4]);
        *reinterpret_cast<u16x4*>(&tile[r][cg * 4]) = v;
    }
    __syncthreads();
#pragma unroll
    for (int p = 0; p < 4; ++p) {
        int idx = p * 256 + t;
        int d = idx >> 4;
        int cg = idx & 15;
        u16x4 o;
        o.x = tile[cg * 4 + 0][d];
        o.y = tile[cg * 4 + 1][d];
        o.z = tile[cg * 4 + 2][d];
        o.w = tile[cg * 4 + 3][d];
        *reinterpret_cast<u16x4*>(
            &Vt[((size_t)nh * 64 + d) * S_LEN + cb * 64 + cg * 4]) = o;
    }
}

// ---------------------------------------------------------------- flash attention
// Block = 4 waves, 64 q-rows, one head. K/V tiles double-buffered in LDS
// (cooperative global_load_lds staging, source-side XOR swizzle), one barrier
// per kb tile, next tile prefetched during compute. Dispatch swizzle: 4 heads
// pinned per XCD (L2 reuse), qb descending (heavy blocks first).
__global__ __launch_bounds__(256) void attn(
    const unsigned short* __restrict__ Z, const unsigned short* __restrict__ Vt,
    float* __restrict__ Out) {
    const int ilin = blockIdx.y * 32 + blockIdx.x;
    const int head32 = (ilin & 7) * 4 + ((ilin >> 3) & 3);   // 4 heads per XCD
    const int qb = 31 - (ilin >> 5);                          // heavy-first
    const int n = head32 >> 4, h = head32 & 15;

    __shared__ unsigned short Kt[2][64 * 64];   // [key_row][64 k-elems] 8 KB x2
    __shared__ unsigned short Vs[2][64 * 64];   // [d_row][64 key-elems] 8 KB x2
    __shared__ unsigned short p_lds[4][16][72];

    const int t = threadIdx.x;
    const int lane = t & 63, w = t >> 6;
    const int lr = lane & 15, lg = lane >> 4;
    const int srow = lane >> 3, sslot = lane & 7;

    // Q fragments (A-operand: row = lane&15, k = (lane>>4)*8 + j)
    const size_t zrowQ = (size_t)(n * S_LEN + qb * 64 + w * 16 + lr) * N3 + D_MODEL + h * HD;
    bf16x8 qf[2];
    qf[0] = *reinterpret_cast<const bf16x8*>(&Z[zrowQ + lg * 8]);
    qf[1] = *reinterpret_cast<const bf16x8*>(&Z[zrowQ + 32 + lg * 8]);

    // wave w stages rows [w*16, w*16+16) of both tiles (2 issues each)
    auto STAGE = [&](int buf, int kb) {
#pragma unroll
        for (int p = 0; p < 2; ++p) {
            int rb = w * 16 + p * 8;            // wave-uniform base row
            int row = rb + srow;
            int seg = sslot ^ (row & 7);
            GLOAD_LDS(&Z[(size_t)(n * S_LEN + kb * 64 + row) * N3 + h * HD + seg * 8],
                      &Kt[buf][rb * 64]);
            GLOAD_LDS(&Vt[((size_t)head32 * 64 + row) * S_LEN + kb * 64 + seg * 8],
                      &Vs[buf][rb * 64]);
        }
    };

    f32x4 o[4] = {};
    float mrun[4], lrun[4];
#pragma unroll
    for (int i = 0; i < 4; ++i) { mrun[i] = -1e30f; lrun[i] = 0.f; }

    const int qrow_base = qb * 64 + w * 16 + lg * 4;

    STAGE(0, 0);
    int cur = 0;
    for (int kb = 0; kb <= qb; ++kb) {
        __syncthreads();   // staging of `cur` complete; all reads of cur^1 done
        if (kb < qb) STAGE(cur ^ 1, kb + 1);
        const unsigned short* Kc = &Kt[cur][0];
        const unsigned short* Vc = &Vs[cur][0];

        // ---- S = Q K^T
        f32x4 s[4];
#pragma unroll
        for (int cf = 0; cf < 4; ++cf) {
            int row = cf * 16 + lr;
            bf16x8 kf0 = *reinterpret_cast<const bf16x8*>(
                &Kc[row * 64 + ((lg) ^ (row & 7)) * 8]);
            bf16x8 kf1 = *reinterpret_cast<const bf16x8*>(
                &Kc[row * 64 + ((lg + 4) ^ (row & 7)) * 8]);
            f32x4 a = {};
            a = __builtin_amdgcn_mfma_f32_16x16x32_bf16(qf[0], kf0, a, 0, 0, 0);
            a = __builtin_amdgcn_mfma_f32_16x16x32_bf16(qf[1], kf1, a, 0, 0, 0);
            s[cf] = a;
        }
        // ---- scale + causal mask
        const bool diag = (kb == qb);
#pragma unroll
        for (int cf = 0; cf < 4; ++cf) {
            int kcol = kb * 64 + cf * 16 + lr;
#pragma unroll
            for (int i = 0; i < 4; ++i) {
                float v = s[cf][i] * 0.03125f;
                if (diag && kcol > qrow_base + i) v = -1e30f;
                s[cf][i] = v;
            }
        }
        // ---- online softmax (rows in 16-lane groups)
#pragma unroll
        for (int i = 0; i < 4; ++i) {
            float v = fmaxf(fmaxf(s[0][i], s[1][i]), fmaxf(s[2][i], s[3][i]));
            v = fmaxf(v, __shfl_xor(v, 1));
            v = fmaxf(v, __shfl_xor(v, 2));
            v = fmaxf(v, __shfl_xor(v, 4));
            v = fmaxf(v, __shfl_xor(v, 8));
            float mn = fmaxf(mrun[i], v);
            float corr = __expf(mrun[i] - mn);
            mrun[i] = mn;
            float sum = 0.f;
#pragma unroll
            for (int cf = 0; cf < 4; ++cf) {
                float p = __expf(s[cf][i] - mn);
                s[cf][i] = p;
                sum += p;
            }
            sum += __shfl_xor(sum, 1);
            sum += __shfl_xor(sum, 2);
            sum += __shfl_xor(sum, 4);
            sum += __shfl_xor(sum, 8);
            lrun[i] = lrun[i] * corr + sum;
#pragma unroll
            for (int cfd = 0; cfd < 4; ++cfd) o[cfd][i] *= corr;
        }
        // ---- P (D-layout) -> per-wave LDS -> A-layout
#pragma unroll
        for (int cf = 0; cf < 4; ++cf)
#pragma unroll
            for (int i = 0; i < 4; ++i)
                p_lds[w][lg * 4 + i][cf * 16 + lr] = f2bf(s[cf][i]);
        // ---- O += P * V
#pragma unroll
        for (int ks = 0; ks < 2; ++ks) {
            bf16x8 pf = *reinterpret_cast<const bf16x8*>(&p_lds[w][lr][ks * 32 + lg * 8]);
#pragma unroll
            for (int cfd = 0; cfd < 4; ++cfd) {
                int vrow = cfd * 16 + lr;
                bf16x8 vf = *reinterpret_cast<const bf16x8*>(
                    &Vc[vrow * 64 + ((ks * 4 + lg) ^ (vrow & 7)) * 8]);
                o[cfd] = __builtin_amdgcn_mfma_f32_16x16x32_bf16(pf, vf, o[cfd], 0, 0, 0);
            }
        }
        cur ^= 1;
    }
    // ---- epilogue
#pragma unroll
    for (int cfd = 0; cfd < 4; ++cfd) {
        int d = h * HD + cfd * 16 + lr;
#pragma unroll
        for (int i = 0; i < 4; ++i) {
            int q = qb * 64 + w * 16 + lg * 4 + i;
            Out[(size_t)(n * S_LEN + q) * D_MODEL + d] = o[cfd][i] / lrun[i];
        }
    }
}

// ----------------------------------------------------------------
extern "C" void kernel_launch(void* const* d_in, const int* in_sizes, int n_in,
                              void* d_out, int out_size, void* d_ws, size_t ws_size,
                              hipStream_t stream) {
    const float* x = (const float*)d_in[0];
    const float* W = (const float*)d_in[1];
    const float* b = (const float*)d_in[2];
    float* out = (float*)d_out;

    char* ws = (char*)d_ws;
    unsigned short* xb = (unsigned short*)ws;                                  // 8 MB
    unsigned short* Wb = (unsigned short*)(ws + (size_t)8 * 1024 * 1024);      // 6 MB
    unsigned short* Z  = (unsigned short*)(ws + (size_t)14 * 1024 * 1024);     // 24 MB
    unsigned short* Vt = (unsigned short*)(ws + (size_t)38 * 1024 * 1024);     // 8 MB

    cast_f32_bf16<<<4096, 256, 0, stream>>>(x, xb, M_TOT * D_MODEL / 4);
    cast_f32_bf16<<<3072, 256, 0, stream>>>(W, Wb, N3 * D_MODEL / 4);
    qkv_gemm<<<dim3(N3 / BN, M_TOT / BM), 256, 0, stream>>>(xb, Wb, b, Z);
    transpose_v<<<1024, 256, 0, stream>>>(Z, Vt);
    attn<<<dim3(S_LEN / 64, NB * NH), 256, 0, stream>>>(Z, Vt, out);
}